// Round 6
// baseline (141.281 us; speedup 1.0000x reference)
//
#include <hip/hip_runtime.h>
#include <hip/hip_bf16.h>

// ---------------------------------------------------------------------------
// LearnedMeans: 2-NN distances (queries=learned_means vs {true_means, X_train})
// + statistics. R6 structure (latency-bound fix: barrier-free A-stationary):
//   1) convert_norms_kernel: f32 -> bf16 copy + row sq-norms
//   2) dist_mfma_kernel: block = 64 q-rows x 512 d-rows. A panel (64x512 bf16,
//      64KB) staged to LDS ONCE (one barrier); 8 waves each own 64 disjoint
//      d-rows and stream B-fragments DIRECTLY global->VGPR (16x16x32 B-frag
//      is a contiguous bf16x8 per lane). Zero main-loop barriers; 1-k-deep
//      B prefetch; 16 waves/CU. A ds_reads bank-conflict-free via 3-bit XOR
//      swizzle (inverse folded into staging source, rule both-sides).
//      XCD-grouped N ownership keeps each 512KB B panel L2-hot.
//   3) reduce_top2_kernel: wave-per-query chunk merge
//   4) stats_kernel: counts/means/percentiles
// Fallback to the verified R2 path if ws_size < ~24 MB.
// ---------------------------------------------------------------------------

#define DIM 512
#define M_Q 1024
#define P_TM 4096
#define P_XT 16384
#define P_ALL (P_TM + P_XT)          // 20480
#define NROWS_ALL (M_Q + P_ALL)      // 21504

#define CHUNK 64
#define NCHUNK_TM (P_TM / CHUNK)     // 64
#define NCHUNK_TOT (P_ALL / CHUNK)   // 320
#define BIGF 3.402823466e38f

typedef __bf16 bf16x8 __attribute__((ext_vector_type(8)));
typedef float f32x4 __attribute__((ext_vector_type(4)));
typedef unsigned short u16x8 __attribute__((ext_vector_type(8)));

__device__ __forceinline__ unsigned short f2bf(float f) {
    unsigned int u = __float_as_uint(f);
    unsigned int r = (u + 0x7fffu + ((u >> 16) & 1u)) >> 16;
    return (unsigned short)r;
}

__device__ __forceinline__ void merge1(float v, float& d1, float& d2) {
    if (v < d1) { d2 = d1; d1 = v; }
    else if (v < d2) { d2 = v; }
}

__device__ __forceinline__ void top2_shfl16(float& d1, float& d2) {
    #pragma unroll
    for (int off = 1; off < 16; off <<= 1) {
        float o1 = __shfl_xor(d1, off);
        float o2 = __shfl_xor(d2, off);
        float n1 = fminf(d1, o1);
        float n2 = fminf(fmaxf(d1, o1), fminf(d2, o2));
        d1 = n1; d2 = n2;
    }
}

__device__ __forceinline__ void async_copy16(const void* g, void* l) {
    __builtin_amdgcn_global_load_lds(
        (const __attribute__((address_space(1))) void*)g,
        (__attribute__((address_space(3))) void*)l,
        16, 0, 0);
}

// ---------------------------------------------------------------------------
// Pass 1: f32 -> bf16 + squared norms. One wave per row (512 elems, 8/lane).
// ---------------------------------------------------------------------------
__global__ __launch_bounds__(256) void convert_norms_kernel(
    const float* __restrict__ Q, const float* __restrict__ TMat,
    const float* __restrict__ XT,
    unsigned short* __restrict__ Qb, unsigned short* __restrict__ Db,
    float* __restrict__ qn, float* __restrict__ dn)
{
    const int wid = threadIdx.x >> 6;
    const int lane = threadIdx.x & 63;
    const int row = blockIdx.x * 4 + wid;

    const float* src;
    unsigned short* dst;
    float* ndst;
    if (row < M_Q) {
        src = Q + (size_t)row * DIM; dst = Qb + (size_t)row * DIM; ndst = qn + row;
    } else {
        int r = row - M_Q;
        src = (row < M_Q + P_TM) ? (TMat + (size_t)r * DIM)
                                 : (XT + (size_t)(row - (M_Q + P_TM)) * DIM);
        dst = Db + (size_t)r * DIM; ndst = dn + r;
    }

    const float* p = src + lane * 8;
    float4 v0 = *(const float4*)p;
    float4 v1 = *(const float4*)(p + 4);
    float s = v0.x*v0.x + v0.y*v0.y + v0.z*v0.z + v0.w*v0.w
            + v1.x*v1.x + v1.y*v1.y + v1.z*v1.z + v1.w*v1.w;

    u16x8 o;
    o[0]=f2bf(v0.x); o[1]=f2bf(v0.y); o[2]=f2bf(v0.z); o[3]=f2bf(v0.w);
    o[4]=f2bf(v1.x); o[5]=f2bf(v1.y); o[6]=f2bf(v1.z); o[7]=f2bf(v1.w);
    *(u16x8*)(dst + lane * 8) = o;

    #pragma unroll
    for (int off = 32; off > 0; off >>= 1) s += __shfl_xor(s, off);
    if (lane == 0) *ndst = s;
}

// ---------------------------------------------------------------------------
// Pass 2: A-stationary MFMA distance + per-64-col-chunk top-2.
//
// Grid: 640 blocks x 512 threads (8 waves). Block (mblk, ngrp):
//   mblk 0..15 -> q-rows [mblk*64, +64);  ngrp 0..39 -> d-rows [ngrp*512, +512)
//   xcd = bid&7 owns ngrp % 8 == xcd  (B panel L2-locality)
// A LDS layout: [64 rows][512 cols] bf16, 1KB/row; 16B chunk c of row r stored
// at c_swz = (c&56) | ((c^r)&7)  (involution; staged with inverse on source).
// Wave wv: d-rows [dBase, dBase+64), acc[4][4] (64 q x 64 d).
// Per k (16 total): 4 B global bf16x8 loads (prefetched k+1) + 4 A ds_reads
// + 16 MFMAs. No barriers after the A-stage barrier.
// ---------------------------------------------------------------------------
__global__ __launch_bounds__(512, 4) void dist_mfma_kernel(
    const unsigned short* __restrict__ Qb,   // [M_Q][DIM] bf16
    const unsigned short* __restrict__ Db,   // [P_ALL][DIM] bf16
    const float* __restrict__ qn,            // [M_Q]
    const float* __restrict__ dn,            // [P_ALL]
    float* __restrict__ partial)             // [M_Q][NCHUNK_TOT][2]
{
    __shared__ __align__(16) unsigned short As[64 * DIM];   // 64 KB

    const int tid = threadIdx.x;
    const int l   = tid & 63;
    const int wv  = tid >> 6;            // 0..7
    const int r15 = l & 15;
    const int h   = l >> 4;              // 0..3
    const int r7  = r15 & 7;

    const int bid  = blockIdx.x;         // 0..639
    const int xcd  = bid & 7;
    const int idx  = bid >> 3;           // 0..79
    const int mblk = idx & 15;
    const int ngrp = xcd + 8 * (idx >> 4);   // 0..39
    const int mBase = mblk * 64;
    const int dBase = ngrp * 512 + wv * 64;

    // ---- stage A panel once: linear LDS dest, inverse-swizzled source ----
    #pragma unroll
    for (int rr = 0; rr < 8; ++rr) {
        const int row  = rr * 8 + wv;                 // wave-uniform
        const int clog = (l & 56) | ((l ^ row) & 7);  // inverse swizzle
        async_copy16(Qb + (size_t)(mBase + row) * DIM + clog * 8,
                     (char*)As + rr * 8192 + wv * 1024 + l * 16);
    }

    // B fragment pointer: lane reads row (dBase + n*16 + r15), 16B at k*64+h*16
    const unsigned short* pB = Db + (size_t)(dBase + r15) * DIM + h * 8;
    // + n*8192 (n*16 rows) + k*32 (ushorts)

    f32x4 acc[4][4];
    #pragma unroll
    for (int mi = 0; mi < 4; ++mi)
        #pragma unroll
        for (int ni = 0; ni < 4; ++ni)
            #pragma unroll
            for (int i = 0; i < 4; ++i) acc[mi][ni][i] = 0.0f;

    __syncthreads();   // A resident (compiler drains vmcnt before barrier)

    const char* asb = (const char*)As;
    // A frag addr: row=(m*16+r15), c_read=k*4+h ->
    //   byte = row*1024 + (k>>1)*128 + ((((k&1)<<2)|h) ^ r7)*16
    const int aE = r15 * 1024 + ((h ^ r7) << 4);
    const int aO = r15 * 1024 + (((4 | h) ^ r7) << 4);

    bf16x8 bc0 = *(const bf16x8*)(pB);
    bf16x8 bc1 = *(const bf16x8*)(pB + 8192);
    bf16x8 bc2 = *(const bf16x8*)(pB + 16384);
    bf16x8 bc3 = *(const bf16x8*)(pB + 24576);

    #pragma unroll
    for (int k = 0; k < 16; ++k) {
        bf16x8 bn0, bn1, bn2, bn3;
        if (k < 15) {
            const int ko = (k + 1) * 32;
            bn0 = *(const bf16x8*)(pB + ko);
            bn1 = *(const bf16x8*)(pB + 8192 + ko);
            bn2 = *(const bf16x8*)(pB + 16384 + ko);
            bn3 = *(const bf16x8*)(pB + 24576 + ko);
        }

        const int ak = ((k & 1) ? aO : aE) + (k >> 1) * 128;

        bf16x8 a0 = *(const bf16x8*)(asb + ak);
        acc[0][0] = __builtin_amdgcn_mfma_f32_16x16x32_bf16(a0, bc0, acc[0][0], 0, 0, 0);
        acc[0][1] = __builtin_amdgcn_mfma_f32_16x16x32_bf16(a0, bc1, acc[0][1], 0, 0, 0);
        acc[0][2] = __builtin_amdgcn_mfma_f32_16x16x32_bf16(a0, bc2, acc[0][2], 0, 0, 0);
        acc[0][3] = __builtin_amdgcn_mfma_f32_16x16x32_bf16(a0, bc3, acc[0][3], 0, 0, 0);

        bf16x8 a1 = *(const bf16x8*)(asb + ak + 16384);
        acc[1][0] = __builtin_amdgcn_mfma_f32_16x16x32_bf16(a1, bc0, acc[1][0], 0, 0, 0);
        acc[1][1] = __builtin_amdgcn_mfma_f32_16x16x32_bf16(a1, bc1, acc[1][1], 0, 0, 0);
        acc[1][2] = __builtin_amdgcn_mfma_f32_16x16x32_bf16(a1, bc2, acc[1][2], 0, 0, 0);
        acc[1][3] = __builtin_amdgcn_mfma_f32_16x16x32_bf16(a1, bc3, acc[1][3], 0, 0, 0);

        bf16x8 a2 = *(const bf16x8*)(asb + ak + 32768);
        acc[2][0] = __builtin_amdgcn_mfma_f32_16x16x32_bf16(a2, bc0, acc[2][0], 0, 0, 0);
        acc[2][1] = __builtin_amdgcn_mfma_f32_16x16x32_bf16(a2, bc1, acc[2][1], 0, 0, 0);
        acc[2][2] = __builtin_amdgcn_mfma_f32_16x16x32_bf16(a2, bc2, acc[2][2], 0, 0, 0);
        acc[2][3] = __builtin_amdgcn_mfma_f32_16x16x32_bf16(a2, bc3, acc[2][3], 0, 0, 0);

        bf16x8 a3 = *(const bf16x8*)(asb + ak + 49152);
        acc[3][0] = __builtin_amdgcn_mfma_f32_16x16x32_bf16(a3, bc0, acc[3][0], 0, 0, 0);
        acc[3][1] = __builtin_amdgcn_mfma_f32_16x16x32_bf16(a3, bc1, acc[3][1], 0, 0, 0);
        acc[3][2] = __builtin_amdgcn_mfma_f32_16x16x32_bf16(a3, bc2, acc[3][2], 0, 0, 0);
        acc[3][3] = __builtin_amdgcn_mfma_f32_16x16x32_bf16(a3, bc3, acc[3][3], 0, 0, 0);

        if (k < 15) { bc0 = bn0; bc1 = bn1; bc2 = bn2; bc3 = bn3; }
    }

    // --- epilogue: sq = q2 + d2 - 2*dot; top-2 per (row, 64-col chunk) ---
    float q2[4][4];
    #pragma unroll
    for (int mi = 0; mi < 4; ++mi)
        #pragma unroll
        for (int r = 0; r < 4; ++r)
            q2[mi][r] = qn[mBase + mi * 16 + h * 4 + r];

    float d1[4][4], d2[4][4];
    #pragma unroll
    for (int mi = 0; mi < 4; ++mi)
        #pragma unroll
        for (int r = 0; r < 4; ++r) { d1[mi][r] = BIGF; d2[mi][r] = BIGF; }

    #pragma unroll
    for (int ni = 0; ni < 4; ++ni) {
        float dd = dn[dBase + ni * 16 + r15];
        #pragma unroll
        for (int mi = 0; mi < 4; ++mi)
            #pragma unroll
            for (int r = 0; r < 4; ++r) {
                float sq = q2[mi][r] + dd - 2.0f * acc[mi][ni][r];
                sq = fmaxf(sq, 0.0f);
                merge1(sq, d1[mi][r], d2[mi][r]);
            }
    }

    #pragma unroll
    for (int mi = 0; mi < 4; ++mi)
        #pragma unroll
        for (int r = 0; r < 4; ++r)
            top2_shfl16(d1[mi][r], d2[mi][r]);

    if (r15 == 0) {
        const int chunkG = ngrp * 8 + wv;
        #pragma unroll
        for (int mi = 0; mi < 4; ++mi)
            #pragma unroll
            for (int r = 0; r < 4; ++r) {
                int row = mBase + mi * 16 + h * 4 + r;
                size_t base = ((size_t)row * NCHUNK_TOT + chunkG) * 2;
                partial[base]     = d1[mi][r];
                partial[base + 1] = d2[mi][r];
            }
    }
}

// ---------------------------------------------------------------------------
// Pass 3: merge per-chunk top-2 partials (one wave per query).
// ---------------------------------------------------------------------------
__global__ __launch_bounds__(256) void reduce_top2_kernel(
    const float* __restrict__ partial, float* __restrict__ fin)
{
    const int wid  = threadIdx.x >> 6;
    const int lane = threadIdx.x & 63;
    const int m = blockIdx.x * 4 + wid;
    const float* p = partial + (size_t)m * (NCHUNK_TOT * 2);

    float2 v = *(const float2*)(p + 2 * lane);
    float a1 = fminf(v.x, v.y), a2 = fmaxf(v.x, v.y);
    #pragma unroll
    for (int off = 32; off > 0; off >>= 1) {
        float o1 = __shfl_xor(a1, off);
        float o2 = __shfl_xor(a2, off);
        float n1 = fminf(a1, o1);
        float n2 = fminf(fmaxf(a1, o1), fminf(a2, o2));
        a1 = n1; a2 = n2;
    }

    const float* px = p + 2 * NCHUNK_TM + lane * 8;
    float4 w0 = *(const float4*)px;
    float4 w1 = *(const float4*)(px + 4);
    float b1 = BIGF, b2 = BIGF;
    merge1(w0.x, b1, b2); merge1(w0.y, b1, b2);
    merge1(w0.z, b1, b2); merge1(w0.w, b1, b2);
    merge1(w1.x, b1, b2); merge1(w1.y, b1, b2);
    merge1(w1.z, b1, b2); merge1(w1.w, b1, b2);
    #pragma unroll
    for (int off = 32; off > 0; off >>= 1) {
        float o1 = __shfl_xor(b1, off);
        float o2 = __shfl_xor(b2, off);
        float n1 = fminf(b1, o1);
        float n2 = fminf(fmaxf(b1, o1), fminf(b2, o2));
        b1 = n1; b2 = n2;
    }

    if (lane == 0) {
        fin[m]           = sqrtf(a1);
        fin[M_Q + m]     = sqrtf(a2);
        fin[2*M_Q + m]   = sqrtf(b1);
        fin[3*M_Q + m]   = sqrtf(b2);
    }
}

// ---------------------------------------------------------------------------
// Pass 4: stats.
// ---------------------------------------------------------------------------
__device__ __forceinline__ void sort_and_pct(float* s, int t, float* dst) {
    __syncthreads();
    for (int k = 2; k <= 1024; k <<= 1) {
        for (int j = k >> 1; j > 0; j >>= 1) {
            __syncthreads();
            int ixj = t ^ j;
            if (ixj > t) {
                float a = s[t], b = s[ixj];
                bool up = ((t & k) == 0);
                if ((a > b) == up) { s[t] = b; s[ixj] = a; }
            }
        }
    }
    __syncthreads();
    if (t < 5) {
        const float P[5] = {10.f, 25.f, 50.f, 75.f, 90.f};
        float q = P[t] * 1023.0f / 100.0f;
        int lo = (int)q;
        float fr = q - (float)lo;
        dst[t] = s[lo] + fr * (s[lo + 1] - s[lo]);
    }
    __syncthreads();
}

__global__ __launch_bounds__(1024) void stats_kernel(
    const float* __restrict__ fin, float* __restrict__ out)
{
    __shared__ float s[1024];
    __shared__ float red[16][6];
    const int t = threadIdx.x;

    float m1 = fin[t];
    float m2 = fin[1024 + t];
    float s1 = fin[2048 + t];
    float s2 = fin[3072 + t];

    const float T = 1.0f / 3.0f;
    float v[6];
    v[0] = (m1 < T * s1 && m1 < T * m2) ? 1.0f : 0.0f;
    v[1] = (s1 < T * m1 && s1 < T * s2) ? 1.0f : 0.0f;
    v[2] = m1; v[3] = s1; v[4] = m2; v[5] = s2;

    #pragma unroll
    for (int off = 32; off > 0; off >>= 1)
        #pragma unroll
        for (int i = 0; i < 6; ++i) v[i] += __shfl_xor(v[i], off);

    int lane = t & 63, wid = t >> 6;
    if (lane == 0) {
        #pragma unroll
        for (int i = 0; i < 6; ++i) red[wid][i] = v[i];
    }
    __syncthreads();
    if (t == 0) {
        float a[6] = {0, 0, 0, 0, 0, 0};
        for (int w = 0; w < 16; ++w)
            for (int i = 0; i < 6; ++i) a[i] += red[w][i];
        out[0] = a[0];
        out[1] = a[1];
        out[2] = a[2] / 1024.0f;
        out[3] = a[3] / 1024.0f;
        out[4] = a[4] / 1024.0f;
        out[5] = a[5] / 1024.0f;
    }

    s[t] = m1;
    sort_and_pct(s, t, out + 6);
    s[t] = s1;
    sort_and_pct(s, t, out + 11);
}

// ---------------------------------------------------------------------------
// Fallback path (verified R2 kernels) — used only if ws_size is too small.
// ---------------------------------------------------------------------------
__global__ __launch_bounds__(256) void norms_kernel_fb(
    const float* __restrict__ src, float* __restrict__ dst, int nrows)
{
    int wid = threadIdx.x >> 6;
    int lane = threadIdx.x & 63;
    int row = blockIdx.x * 4 + wid;
    if (row >= nrows) return;
    const float* p = src + (size_t)row * DIM + lane * 8;
    float4 v0 = *(const float4*)p;
    float4 v1 = *(const float4*)(p + 4);
    float s = v0.x*v0.x + v0.y*v0.y + v0.z*v0.z + v0.w*v0.w
            + v1.x*v1.x + v1.y*v1.y + v1.z*v1.z + v1.w*v1.w;
    #pragma unroll
    for (int off = 32; off > 0; off >>= 1) s += __shfl_xor(s, off);
    if (lane == 0) dst[row] = s;
}

__global__ __launch_bounds__(256) void dist_top2_kernel_fb(
    const float* __restrict__ Q, const float* __restrict__ Dset,
    const float* __restrict__ qn, const float* __restrict__ dn,
    float* __restrict__ partial, int chunkGlobalOffset)
{
    __shared__ __align__(16) unsigned short As[64][40];
    __shared__ __align__(16) unsigned short Bs[64][40];

    const int tid  = threadIdx.x;
    const int lane = tid & 63;
    const int wid  = tid >> 6;
    const int mBase = blockIdx.y * 64;
    const int nBase = blockIdx.x * 64;

    const int srow = tid >> 2;
    const int skc  = (tid & 3) * 8;

    const float* qrow = Q    + (size_t)(mBase + srow) * DIM + skc;
    const float* drow = Dset + (size_t)(nBase + srow) * DIM + skc;

    f32x4 acc[4];
    #pragma unroll
    for (int nt = 0; nt < 4; ++nt)
        #pragma unroll
        for (int i = 0; i < 4; ++i) acc[nt][i] = 0.0f;

    const int frow = lane & 15;
    const int fk   = (lane >> 4) * 8;

    for (int ks = 0; ks < DIM; ks += 32) {
        float4 a0 = *(const float4*)(qrow + ks);
        float4 a1 = *(const float4*)(qrow + ks + 4);
        float4 b0 = *(const float4*)(drow + ks);
        float4 b1 = *(const float4*)(drow + ks + 4);

        u16x8 va, vb;
        va[0]=f2bf(a0.x); va[1]=f2bf(a0.y); va[2]=f2bf(a0.z); va[3]=f2bf(a0.w);
        va[4]=f2bf(a1.x); va[5]=f2bf(a1.y); va[6]=f2bf(a1.z); va[7]=f2bf(a1.w);
        vb[0]=f2bf(b0.x); vb[1]=f2bf(b0.y); vb[2]=f2bf(b0.z); vb[3]=f2bf(b0.w);
        vb[4]=f2bf(b1.x); vb[5]=f2bf(b1.y); vb[6]=f2bf(b1.z); vb[7]=f2bf(b1.w);

        *(u16x8*)(&As[srow][skc]) = va;
        *(u16x8*)(&Bs[srow][skc]) = vb;
        __syncthreads();

        bf16x8 af = *(const bf16x8*)(&As[wid * 16 + frow][fk]);
        #pragma unroll
        for (int nt = 0; nt < 4; ++nt) {
            bf16x8 bf = *(const bf16x8*)(&Bs[nt * 16 + frow][fk]);
            acc[nt] = __builtin_amdgcn_mfma_f32_16x16x32_bf16(af, bf, acc[nt], 0, 0, 0);
        }
        __syncthreads();
    }

    const int rbase = mBase + wid * 16 + ((lane >> 4) << 2);
    float q2[4];
    #pragma unroll
    for (int r = 0; r < 4; ++r) q2[r] = qn[rbase + r];

    float d1[4], d2[4];
    #pragma unroll
    for (int r = 0; r < 4; ++r) { d1[r] = BIGF; d2[r] = BIGF; }

    #pragma unroll
    for (int nt = 0; nt < 4; ++nt) {
        float dd = dn[nBase + nt * 16 + (lane & 15)];
        #pragma unroll
        for (int r = 0; r < 4; ++r) {
            float sq = q2[r] + dd - 2.0f * acc[nt][r];
            sq = fmaxf(sq, 0.0f);
            merge1(sq, d1[r], d2[r]);
        }
    }

    #pragma unroll
    for (int r = 0; r < 4; ++r) top2_shfl16(d1[r], d2[r]);

    if ((lane & 15) == 0) {
        int chunkG = chunkGlobalOffset + blockIdx.x;
        #pragma unroll
        for (int r = 0; r < 4; ++r) {
            size_t base = ((size_t)(rbase + r) * NCHUNK_TOT + chunkG) * 2;
            partial[base]     = d1[r];
            partial[base + 1] = d2[r];
        }
    }
}

// ---------------------------------------------------------------------------
extern "C" void kernel_launch(void* const* d_in, const int* in_sizes, int n_in,
                              void* d_out, int out_size, void* d_ws, size_t ws_size,
                              hipStream_t stream) {
    const float* Q  = (const float*)d_in[0];
    const float* TM = (const float*)d_in[1];
    const float* XT = (const float*)d_in[2];
    float* out = (float*)d_out;

    const size_t needMain =
        (size_t)M_Q * DIM * 2 + (size_t)P_ALL * DIM * 2 +
        4 * ((size_t)M_Q + P_ALL + (size_t)M_Q * NCHUNK_TOT * 2 + 4 * M_Q);

    if (ws_size >= needMain) {
        char* w = (char*)d_ws;
        unsigned short* Qb = (unsigned short*)w;
        unsigned short* Db = (unsigned short*)(w + (size_t)M_Q * DIM * 2);
        float* qn = (float*)(w + (size_t)M_Q * DIM * 2 + (size_t)P_ALL * DIM * 2);
        float* dn = qn + M_Q;
        float* partial = dn + P_ALL;
        float* fin = partial + (size_t)M_Q * NCHUNK_TOT * 2;

        convert_norms_kernel<<<dim3(NROWS_ALL / 4), 256, 0, stream>>>(
            Q, TM, XT, Qb, Db, qn, dn);
        dist_mfma_kernel<<<dim3(640), 512, 0, stream>>>(
            Qb, Db, qn, dn, partial);
        reduce_top2_kernel<<<dim3(M_Q / 4), 256, 0, stream>>>(partial, fin);
        stats_kernel<<<dim3(1), 1024, 0, stream>>>(fin, out);
    } else {
        float* ws = (float*)d_ws;
        float* qn = ws;
        float* dn = ws + M_Q;
        float* partial = dn + P_ALL;
        float* fin = partial + (size_t)M_Q * NCHUNK_TOT * 2;

        norms_kernel_fb<<<dim3(M_Q / 4),  256, 0, stream>>>(Q,  qn, M_Q);
        norms_kernel_fb<<<dim3(P_TM / 4), 256, 0, stream>>>(TM, dn, P_TM);
        norms_kernel_fb<<<dim3(P_XT / 4), 256, 0, stream>>>(XT, dn + P_TM, P_XT);
        dist_top2_kernel_fb<<<dim3(P_TM / 64, M_Q / 64), 256, 0, stream>>>(
            Q, TM, qn, dn, partial, 0);
        dist_top2_kernel_fb<<<dim3(P_XT / 64, M_Q / 64), 256, 0, stream>>>(
            Q, XT, qn, dn + P_TM, partial, NCHUNK_TM);
        reduce_top2_kernel<<<dim3(M_Q / 4), 256, 0, stream>>>(partial, fin);
        stats_kernel<<<dim3(1), 1024, 0, stream>>>(fin, out);
    }
}

// Round 8
// 101.307 us; speedup vs baseline: 1.3946x; 1.3946x over previous
//
#include <hip/hip_runtime.h>
#include <hip/hip_bf16.h>

// ---------------------------------------------------------------------------
// LearnedMeans: 2-NN distances (queries=learned_means vs {true_means, X_train})
// + statistics. R8 = R7 with the compile fix (stray placeholder removed):
//   1) convert_norms_kernel: f32 -> bf16 copy + row sq-norms
//   2) dist_mfma_kernel: R2's PROVEN 64x64-tile / 4-wave / 2-barrier loop
//      (71% occupancy measured) minus its waste: bf16 pre-converted inputs
//      (half the staged bytes, no in-loop f32->bf16 repack), BK=64 (half the
//      barriers), fused single dispatch over concatenated D (5120 blocks),
//      1-step register prefetch, XOR-swizzled LDS (2 lanes/bank = free).
//      Footprint kept tiny on purpose: 16 KB LDS, VGPR<=85 -> many blocks/CU.
//   3) reduce_top2_kernel: wave-per-query chunk merge
//   4) stats_kernel: counts/means/percentiles
// Fallback to the verified R2 path if ws_size < ~24 MB.
// ---------------------------------------------------------------------------

#define DIM 512
#define M_Q 1024
#define P_TM 4096
#define P_XT 16384
#define P_ALL (P_TM + P_XT)          // 20480
#define NROWS_ALL (M_Q + P_ALL)      // 21504

#define BK 64
#define NSTEP (DIM / BK)             // 8
#define CHUNK 64
#define NCHUNK_TM (P_TM / CHUNK)     // 64
#define NCHUNK_TOT (P_ALL / CHUNK)   // 320
#define BIGF 3.402823466e38f

typedef __bf16 bf16x8 __attribute__((ext_vector_type(8)));
typedef float f32x4 __attribute__((ext_vector_type(4)));
typedef unsigned short u16x8 __attribute__((ext_vector_type(8)));

__device__ __forceinline__ unsigned short f2bf(float f) {
    unsigned int u = __float_as_uint(f);
    unsigned int r = (u + 0x7fffu + ((u >> 16) & 1u)) >> 16;
    return (unsigned short)r;
}

__device__ __forceinline__ void merge1(float v, float& d1, float& d2) {
    if (v < d1) { d2 = d1; d1 = v; }
    else if (v < d2) { d2 = v; }
}

__device__ __forceinline__ void top2_shfl16(float& d1, float& d2) {
    #pragma unroll
    for (int off = 1; off < 16; off <<= 1) {
        float o1 = __shfl_xor(d1, off);
        float o2 = __shfl_xor(d2, off);
        float n1 = fminf(d1, o1);
        float n2 = fminf(fmaxf(d1, o1), fminf(d2, o2));
        d1 = n1; d2 = n2;
    }
}

// ---------------------------------------------------------------------------
// Pass 1: f32 -> bf16 + squared norms. One wave per row (512 elems, 8/lane).
// ---------------------------------------------------------------------------
__global__ __launch_bounds__(256) void convert_norms_kernel(
    const float* __restrict__ Q, const float* __restrict__ TMat,
    const float* __restrict__ XT,
    unsigned short* __restrict__ Qb, unsigned short* __restrict__ Db,
    float* __restrict__ qn, float* __restrict__ dn)
{
    const int wid = threadIdx.x >> 6;
    const int lane = threadIdx.x & 63;
    const int row = blockIdx.x * 4 + wid;

    const float* src;
    unsigned short* dst;
    float* ndst;
    if (row < M_Q) {
        src = Q + (size_t)row * DIM; dst = Qb + (size_t)row * DIM; ndst = qn + row;
    } else {
        int r = row - M_Q;
        src = (row < M_Q + P_TM) ? (TMat + (size_t)r * DIM)
                                 : (XT + (size_t)(row - (M_Q + P_TM)) * DIM);
        dst = Db + (size_t)r * DIM; ndst = dn + r;
    }

    const float* p = src + lane * 8;
    float4 v0 = *(const float4*)p;
    float4 v1 = *(const float4*)(p + 4);
    float s = v0.x*v0.x + v0.y*v0.y + v0.z*v0.z + v0.w*v0.w
            + v1.x*v1.x + v1.y*v1.y + v1.z*v1.z + v1.w*v1.w;

    u16x8 o;
    o[0]=f2bf(v0.x); o[1]=f2bf(v0.y); o[2]=f2bf(v0.z); o[3]=f2bf(v0.w);
    o[4]=f2bf(v1.x); o[5]=f2bf(v1.y); o[6]=f2bf(v1.z); o[7]=f2bf(v1.w);
    *(u16x8*)(dst + lane * 8) = o;

    #pragma unroll
    for (int off = 32; off > 0; off >>= 1) s += __shfl_xor(s, off);
    if (lane == 0) *ndst = s;
}

// ---------------------------------------------------------------------------
// Pass 2: 64x64-tile MFMA distance + per-chunk top-2 (R2 structure, bf16).
// Grid: (320 n-chunks, 16 m-blocks), 256 threads (4 waves).
// Wave w owns A-rows [w*16, w*16+16) x all 64 d-cols -> acc[4] of 16x16.
// LDS: As/Bs [64 rows][64 bf16] = 128B row = 8 x 16B chunks; chunk c of row
// r stored at c^(r&7) (reads AND writes 2 lanes/bank = free).
// Per K-step: 4x u16x8 global prefetch (reg, issued 1 step early), 2 kh x
// (1 A ds_read + 4 B ds_read + 4 MFMA), 2 barriers.
// ---------------------------------------------------------------------------
__global__ __launch_bounds__(256, 6) void dist_mfma_kernel(
    const unsigned short* __restrict__ Qb,   // [M_Q][DIM] bf16
    const unsigned short* __restrict__ Db,   // [P_ALL][DIM] bf16
    const float* __restrict__ qn,            // [M_Q]
    const float* __restrict__ dn,            // [P_ALL]
    float* __restrict__ partial)             // [M_Q][NCHUNK_TOT][2]
{
    __shared__ __align__(16) unsigned short As[64 * 64];  // 8 KB
    __shared__ __align__(16) unsigned short Bs[64 * 64];  // 8 KB

    const int tid  = threadIdx.x;
    const int lane = tid & 63;
    const int wid  = tid >> 6;          // 0..3
    const int r15  = lane & 15;
    const int h    = lane >> 4;         // 0..3
    const int mBase = blockIdx.y * 64;
    const int nBase = blockIdx.x * 64;

    // --- staging mapping: thread t -> row t>>2, chunks (t&3)*2, +1 ---
    const int srow  = tid >> 2;          // 0..63
    const int cpair = (tid & 3) * 2;     // 0,2,4,6
    const unsigned short* gA = Qb + (size_t)(mBase + srow) * DIM + cpair * 8;
    const unsigned short* gB = Db + (size_t)(nBase + srow) * DIM + cpair * 8;
    const int wA0 = srow * 64 + ((cpair       ^ (srow & 7)) << 3);
    const int wA1 = srow * 64 + (((cpair + 1) ^ (srow & 7)) << 3);

    // --- ds_read addresses (ushort idx); B: + n*1024 for n-th 16-row group ---
    const int aA0 = (wid * 16 + r15) * 64 + (((h    ) ^ (r15 & 7)) << 3);
    const int aA1 = (wid * 16 + r15) * 64 + (((4 | h) ^ (r15 & 7)) << 3);
    const int bB0 = r15 * 64 + (((h    ) ^ (r15 & 7)) << 3);
    const int bB1 = r15 * 64 + (((4 | h) ^ (r15 & 7)) << 3);

    f32x4 acc0, acc1, acc2, acc3;
    #pragma unroll
    for (int i = 0; i < 4; ++i) { acc0[i]=0.f; acc1[i]=0.f; acc2[i]=0.f; acc3[i]=0.f; }

    // --- prologue: stage K-step 0 ---
    u16x8 pa0 = *(const u16x8*)(gA);
    u16x8 pa1 = *(const u16x8*)(gA + 8);
    u16x8 pb0 = *(const u16x8*)(gB);
    u16x8 pb1 = *(const u16x8*)(gB + 8);
    *(u16x8*)(&As[wA0]) = pa0;
    *(u16x8*)(&As[wA1]) = pa1;
    *(u16x8*)(&Bs[wA0]) = pb0;
    *(u16x8*)(&Bs[wA1]) = pb1;
    __syncthreads();

    #pragma unroll
    for (int t = 0; t < NSTEP; ++t) {
        if (t + 1 < NSTEP) {
            const int ko = (t + 1) * BK;
            pa0 = *(const u16x8*)(gA + ko);
            pa1 = *(const u16x8*)(gA + ko + 8);
            pb0 = *(const u16x8*)(gB + ko);
            pb1 = *(const u16x8*)(gB + ko + 8);
        }

        // kh = 0
        {
            bf16x8 af = *(const bf16x8*)(&As[aA0]);
            bf16x8 b0 = *(const bf16x8*)(&Bs[bB0]);
            bf16x8 b1 = *(const bf16x8*)(&Bs[bB0 + 1024]);
            bf16x8 b2 = *(const bf16x8*)(&Bs[bB0 + 2048]);
            bf16x8 b3 = *(const bf16x8*)(&Bs[bB0 + 3072]);
            acc0 = __builtin_amdgcn_mfma_f32_16x16x32_bf16(af, b0, acc0, 0, 0, 0);
            acc1 = __builtin_amdgcn_mfma_f32_16x16x32_bf16(af, b1, acc1, 0, 0, 0);
            acc2 = __builtin_amdgcn_mfma_f32_16x16x32_bf16(af, b2, acc2, 0, 0, 0);
            acc3 = __builtin_amdgcn_mfma_f32_16x16x32_bf16(af, b3, acc3, 0, 0, 0);
        }
        // kh = 1
        {
            bf16x8 af = *(const bf16x8*)(&As[aA1]);
            bf16x8 b0 = *(const bf16x8*)(&Bs[bB1]);
            bf16x8 b1 = *(const bf16x8*)(&Bs[bB1 + 1024]);
            bf16x8 b2 = *(const bf16x8*)(&Bs[bB1 + 2048]);
            bf16x8 b3 = *(const bf16x8*)(&Bs[bB1 + 3072]);
            acc0 = __builtin_amdgcn_mfma_f32_16x16x32_bf16(af, b0, acc0, 0, 0, 0);
            acc1 = __builtin_amdgcn_mfma_f32_16x16x32_bf16(af, b1, acc1, 0, 0, 0);
            acc2 = __builtin_amdgcn_mfma_f32_16x16x32_bf16(af, b2, acc2, 0, 0, 0);
            acc3 = __builtin_amdgcn_mfma_f32_16x16x32_bf16(af, b3, acc3, 0, 0, 0);
        }

        __syncthreads();                 // done reading LDS for step t

        if (t + 1 < NSTEP) {
            *(u16x8*)(&As[wA0]) = pa0;
            *(u16x8*)(&As[wA1]) = pa1;
            *(u16x8*)(&Bs[wA0]) = pb0;
            *(u16x8*)(&Bs[wA1]) = pb1;
            __syncthreads();             // LDS ready for step t+1
        }
    }

    // --- epilogue (R2-verified conventions): row=rbase+r, col=nBase+nt*16+r15
    const int rbase = mBase + wid * 16 + (h << 2);
    float q2[4];
    #pragma unroll
    for (int r = 0; r < 4; ++r) q2[r] = qn[rbase + r];

    float d1[4], d2[4];
    #pragma unroll
    for (int r = 0; r < 4; ++r) { d1[r] = BIGF; d2[r] = BIGF; }

    #pragma unroll
    for (int nt = 0; nt < 4; ++nt) {
        float dd = dn[nBase + nt * 16 + r15];
        const f32x4& a = (nt == 0) ? acc0 : (nt == 1) ? acc1 : (nt == 2) ? acc2 : acc3;
        #pragma unroll
        for (int r = 0; r < 4; ++r) {
            float sq = q2[r] + dd - 2.0f * a[r];
            sq = fmaxf(sq, 0.0f);
            merge1(sq, d1[r], d2[r]);
        }
    }

    #pragma unroll
    for (int r = 0; r < 4; ++r) top2_shfl16(d1[r], d2[r]);

    if (r15 == 0) {
        const int chunkG = blockIdx.x;
        #pragma unroll
        for (int r = 0; r < 4; ++r) {
            size_t base = ((size_t)(rbase + r) * NCHUNK_TOT + chunkG) * 2;
            partial[base]     = d1[r];
            partial[base + 1] = d2[r];
        }
    }
}

// ---------------------------------------------------------------------------
// Pass 3: merge per-chunk top-2 partials (one wave per query).
// ---------------------------------------------------------------------------
__global__ __launch_bounds__(256) void reduce_top2_kernel(
    const float* __restrict__ partial, float* __restrict__ fin)
{
    const int wid  = threadIdx.x >> 6;
    const int lane = threadIdx.x & 63;
    const int m = blockIdx.x * 4 + wid;
    const float* p = partial + (size_t)m * (NCHUNK_TOT * 2);

    float2 v = *(const float2*)(p + 2 * lane);
    float a1 = fminf(v.x, v.y), a2 = fmaxf(v.x, v.y);
    #pragma unroll
    for (int off = 32; off > 0; off >>= 1) {
        float o1 = __shfl_xor(a1, off);
        float o2 = __shfl_xor(a2, off);
        float n1 = fminf(a1, o1);
        float n2 = fminf(fmaxf(a1, o1), fminf(a2, o2));
        a1 = n1; a2 = n2;
    }

    const float* px = p + 2 * NCHUNK_TM + lane * 8;
    float4 w0 = *(const float4*)px;
    float4 w1 = *(const float4*)(px + 4);
    float b1 = BIGF, b2 = BIGF;
    merge1(w0.x, b1, b2); merge1(w0.y, b1, b2);
    merge1(w0.z, b1, b2); merge1(w0.w, b1, b2);
    merge1(w1.x, b1, b2); merge1(w1.y, b1, b2);
    merge1(w1.z, b1, b2); merge1(w1.w, b1, b2);
    #pragma unroll
    for (int off = 32; off > 0; off >>= 1) {
        float o1 = __shfl_xor(b1, off);
        float o2 = __shfl_xor(b2, off);
        float n1 = fminf(b1, o1);
        float n2 = fminf(fmaxf(b1, o1), fminf(b2, o2));
        b1 = n1; b2 = n2;
    }

    if (lane == 0) {
        fin[m]           = sqrtf(a1);
        fin[M_Q + m]     = sqrtf(a2);
        fin[2*M_Q + m]   = sqrtf(b1);
        fin[3*M_Q + m]   = sqrtf(b2);
    }
}

// ---------------------------------------------------------------------------
// Pass 4: stats.
// ---------------------------------------------------------------------------
__device__ __forceinline__ void sort_and_pct(float* s, int t, float* dst) {
    __syncthreads();
    for (int k = 2; k <= 1024; k <<= 1) {
        for (int j = k >> 1; j > 0; j >>= 1) {
            __syncthreads();
            int ixj = t ^ j;
            if (ixj > t) {
                float a = s[t], b = s[ixj];
                bool up = ((t & k) == 0);
                if ((a > b) == up) { s[t] = b; s[ixj] = a; }
            }
        }
    }
    __syncthreads();
    if (t < 5) {
        const float P[5] = {10.f, 25.f, 50.f, 75.f, 90.f};
        float q = P[t] * 1023.0f / 100.0f;
        int lo = (int)q;
        float fr = q - (float)lo;
        dst[t] = s[lo] + fr * (s[lo + 1] - s[lo]);
    }
    __syncthreads();
}

__global__ __launch_bounds__(1024) void stats_kernel(
    const float* __restrict__ fin, float* __restrict__ out)
{
    __shared__ float s[1024];
    __shared__ float red[16][6];
    const int t = threadIdx.x;

    float m1 = fin[t];
    float m2 = fin[1024 + t];
    float s1 = fin[2048 + t];
    float s2 = fin[3072 + t];

    const float T = 1.0f / 3.0f;
    float v[6];
    v[0] = (m1 < T * s1 && m1 < T * m2) ? 1.0f : 0.0f;
    v[1] = (s1 < T * m1 && s1 < T * s2) ? 1.0f : 0.0f;
    v[2] = m1; v[3] = s1; v[4] = m2; v[5] = s2;

    #pragma unroll
    for (int off = 32; off > 0; off >>= 1)
        #pragma unroll
        for (int i = 0; i < 6; ++i) v[i] += __shfl_xor(v[i], off);

    int lane = t & 63, wid = t >> 6;
    if (lane == 0) {
        #pragma unroll
        for (int i = 0; i < 6; ++i) red[wid][i] = v[i];
    }
    __syncthreads();
    if (t == 0) {
        float a[6] = {0, 0, 0, 0, 0, 0};
        for (int w = 0; w < 16; ++w)
            for (int i = 0; i < 6; ++i) a[i] += red[w][i];
        out[0] = a[0];
        out[1] = a[1];
        out[2] = a[2] / 1024.0f;
        out[3] = a[3] / 1024.0f;
        out[4] = a[4] / 1024.0f;
        out[5] = a[5] / 1024.0f;
    }

    s[t] = m1;
    sort_and_pct(s, t, out + 6);
    s[t] = s1;
    sort_and_pct(s, t, out + 11);
}

// ---------------------------------------------------------------------------
// Fallback path (verified R2 kernels) — used only if ws_size is too small.
// ---------------------------------------------------------------------------
__global__ __launch_bounds__(256) void norms_kernel_fb(
    const float* __restrict__ src, float* __restrict__ dst, int nrows)
{
    int wid = threadIdx.x >> 6;
    int lane = threadIdx.x & 63;
    int row = blockIdx.x * 4 + wid;
    if (row >= nrows) return;
    const float* p = src + (size_t)row * DIM + lane * 8;
    float4 v0 = *(const float4*)p;
    float4 v1 = *(const float4*)(p + 4);
    float s = v0.x*v0.x + v0.y*v0.y + v0.z*v0.z + v0.w*v0.w
            + v1.x*v1.x + v1.y*v1.y + v1.z*v1.z + v1.w*v1.w;
    #pragma unroll
    for (int off = 32; off > 0; off >>= 1) s += __shfl_xor(s, off);
    if (lane == 0) dst[row] = s;
}

__global__ __launch_bounds__(256) void dist_top2_kernel_fb(
    const float* __restrict__ Q, const float* __restrict__ Dset,
    const float* __restrict__ qn, const float* __restrict__ dn,
    float* __restrict__ partial, int chunkGlobalOffset)
{
    __shared__ __align__(16) unsigned short As[64][40];
    __shared__ __align__(16) unsigned short Bs[64][40];

    const int tid  = threadIdx.x;
    const int lane = tid & 63;
    const int wid  = tid >> 6;
    const int mBase = blockIdx.y * 64;
    const int nBase = blockIdx.x * 64;

    const int srow = tid >> 2;
    const int skc  = (tid & 3) * 8;

    const float* qrow = Q    + (size_t)(mBase + srow) * DIM + skc;
    const float* drow = Dset + (size_t)(nBase + srow) * DIM + skc;

    f32x4 acc[4];
    #pragma unroll
    for (int nt = 0; nt < 4; ++nt)
        #pragma unroll
        for (int i = 0; i < 4; ++i) acc[nt][i] = 0.0f;

    const int frow = lane & 15;
    const int fk   = (lane >> 4) * 8;

    for (int ks = 0; ks < DIM; ks += 32) {
        float4 a0 = *(const float4*)(qrow + ks);
        float4 a1 = *(const float4*)(qrow + ks + 4);
        float4 b0 = *(const float4*)(drow + ks);
        float4 b1 = *(const float4*)(drow + ks + 4);

        u16x8 va, vb;
        va[0]=f2bf(a0.x); va[1]=f2bf(a0.y); va[2]=f2bf(a0.z); va[3]=f2bf(a0.w);
        va[4]=f2bf(a1.x); va[5]=f2bf(a1.y); va[6]=f2bf(a1.z); va[7]=f2bf(a1.w);
        vb[0]=f2bf(b0.x); vb[1]=f2bf(b0.y); vb[2]=f2bf(b0.z); vb[3]=f2bf(b0.w);
        vb[4]=f2bf(b1.x); vb[5]=f2bf(b1.y); vb[6]=f2bf(b1.z); vb[7]=f2bf(b1.w);

        *(u16x8*)(&As[srow][skc]) = va;
        *(u16x8*)(&Bs[srow][skc]) = vb;
        __syncthreads();

        bf16x8 af = *(const bf16x8*)(&As[wid * 16 + frow][fk]);
        #pragma unroll
        for (int nt = 0; nt < 4; ++nt) {
            bf16x8 bf = *(const bf16x8*)(&Bs[nt * 16 + frow][fk]);
            acc[nt] = __builtin_amdgcn_mfma_f32_16x16x32_bf16(af, bf, acc[nt], 0, 0, 0);
        }
        __syncthreads();
    }

    const int rbase = mBase + wid * 16 + ((lane >> 4) << 2);
    float q2[4];
    #pragma unroll
    for (int r = 0; r < 4; ++r) q2[r] = qn[rbase + r];

    float d1[4], d2[4];
    #pragma unroll
    for (int r = 0; r < 4; ++r) { d1[r] = BIGF; d2[r] = BIGF; }

    #pragma unroll
    for (int nt = 0; nt < 4; ++nt) {
        float dd = dn[nBase + nt * 16 + (lane & 15)];
        #pragma unroll
        for (int r = 0; r < 4; ++r) {
            float sq = q2[r] + dd - 2.0f * acc[nt][r];
            sq = fmaxf(sq, 0.0f);
            merge1(sq, d1[r], d2[r]);
        }
    }

    #pragma unroll
    for (int r = 0; r < 4; ++r) top2_shfl16(d1[r], d2[r]);

    if ((lane & 15) == 0) {
        int chunkG = chunkGlobalOffset + blockIdx.x;
        #pragma unroll
        for (int r = 0; r < 4; ++r) {
            size_t base = ((size_t)(rbase + r) * NCHUNK_TOT + chunkG) * 2;
            partial[base]     = d1[r];
            partial[base + 1] = d2[r];
        }
    }
}

// ---------------------------------------------------------------------------
extern "C" void kernel_launch(void* const* d_in, const int* in_sizes, int n_in,
                              void* d_out, int out_size, void* d_ws, size_t ws_size,
                              hipStream_t stream) {
    const float* Q  = (const float*)d_in[0];
    const float* TM = (const float*)d_in[1];
    const float* XT = (const float*)d_in[2];
    float* out = (float*)d_out;

    const size_t needMain =
        (size_t)M_Q * DIM * 2 + (size_t)P_ALL * DIM * 2 +
        4 * ((size_t)M_Q + P_ALL + (size_t)M_Q * NCHUNK_TOT * 2 + 4 * M_Q);

    if (ws_size >= needMain) {
        char* w = (char*)d_ws;
        unsigned short* Qb = (unsigned short*)w;
        unsigned short* Db = (unsigned short*)(w + (size_t)M_Q * DIM * 2);
        float* qn = (float*)(w + (size_t)M_Q * DIM * 2 + (size_t)P_ALL * DIM * 2);
        float* dn = qn + M_Q;
        float* partial = dn + P_ALL;
        float* fin = partial + (size_t)M_Q * NCHUNK_TOT * 2;

        convert_norms_kernel<<<dim3(NROWS_ALL / 4), 256, 0, stream>>>(
            Q, TM, XT, Qb, Db, qn, dn);
        dist_mfma_kernel<<<dim3(NCHUNK_TOT, M_Q / 64), 256, 0, stream>>>(
            Qb, Db, qn, dn, partial);
        reduce_top2_kernel<<<dim3(M_Q / 4), 256, 0, stream>>>(partial, fin);
        stats_kernel<<<dim3(1), 1024, 0, stream>>>(fin, out);
    } else {
        float* ws = (float*)d_ws;
        float* qn = ws;
        float* dn = ws + M_Q;
        float* partial = dn + P_ALL;
        float* fin = partial + (size_t)M_Q * NCHUNK_TOT * 2;

        norms_kernel_fb<<<dim3(M_Q / 4),  256, 0, stream>>>(Q,  qn, M_Q);
        norms_kernel_fb<<<dim3(P_TM / 4), 256, 0, stream>>>(TM, dn, P_TM);
        norms_kernel_fb<<<dim3(P_XT / 4), 256, 0, stream>>>(XT, dn + P_TM, P_XT);
        dist_top2_kernel_fb<<<dim3(P_TM / 64, M_Q / 64), 256, 0, stream>>>(
            Q, TM, qn, dn, partial, 0);
        dist_top2_kernel_fb<<<dim3(P_XT / 64, M_Q / 64), 256, 0, stream>>>(
            Q, XT, qn, dn + P_TM, partial, NCHUNK_TM);
        reduce_top2_kernel<<<dim3(M_Q / 4), 256, 0, stream>>>(partial, fin);
        stats_kernel<<<dim3(1), 1024, 0, stream>>>(fin, out);
    }
}

// Round 9
// 97.640 us; speedup vs baseline: 1.4470x; 1.0376x over previous
//
#include <hip/hip_runtime.h>
#include <hip/hip_bf16.h>

// ---------------------------------------------------------------------------
// LearnedMeans: 2-NN distances + statistics. R9 = R8 plus:
//   - XCD-aware sweep remap in dist_mfma_kernel: per XCD, 16 consecutive
//     blocks share ONE n-chunk (64KB B-tile L2-resident across 16 reuses)
//     while sweeping m-blocks (A panel 1MB stays L2-hot across sweeps).
//     R8 evidence: all staging missed L2 (FETCH 88MB, 2.8TB/s L3 traffic,
//     MfmaUtil 11% at 63% occupancy) -> L2-miss latency bound.
//   - launch_bounds(256,8): 8 blocks/CU (was capped at ~5).
//   - stats_kernel: both percentile arrays sorted in ONE bitonic pass.
// Fallback to the verified R2 path if ws_size < ~24 MB.
// ---------------------------------------------------------------------------

#define DIM 512
#define M_Q 1024
#define P_TM 4096
#define P_XT 16384
#define P_ALL (P_TM + P_XT)          // 20480
#define NROWS_ALL (M_Q + P_ALL)      // 21504

#define BK 64
#define NSTEP (DIM / BK)             // 8
#define CHUNK 64
#define NCHUNK_TM (P_TM / CHUNK)     // 64
#define NCHUNK_TOT (P_ALL / CHUNK)   // 320
#define BIGF 3.402823466e38f

typedef __bf16 bf16x8 __attribute__((ext_vector_type(8)));
typedef float f32x4 __attribute__((ext_vector_type(4)));
typedef unsigned short u16x8 __attribute__((ext_vector_type(8)));

__device__ __forceinline__ unsigned short f2bf(float f) {
    unsigned int u = __float_as_uint(f);
    unsigned int r = (u + 0x7fffu + ((u >> 16) & 1u)) >> 16;
    return (unsigned short)r;
}

__device__ __forceinline__ void merge1(float v, float& d1, float& d2) {
    if (v < d1) { d2 = d1; d1 = v; }
    else if (v < d2) { d2 = v; }
}

__device__ __forceinline__ void top2_shfl16(float& d1, float& d2) {
    #pragma unroll
    for (int off = 1; off < 16; off <<= 1) {
        float o1 = __shfl_xor(d1, off);
        float o2 = __shfl_xor(d2, off);
        float n1 = fminf(d1, o1);
        float n2 = fminf(fmaxf(d1, o1), fminf(d2, o2));
        d1 = n1; d2 = n2;
    }
}

// ---------------------------------------------------------------------------
// Pass 1: f32 -> bf16 + squared norms. One wave per row (512 elems, 8/lane).
// ---------------------------------------------------------------------------
__global__ __launch_bounds__(256) void convert_norms_kernel(
    const float* __restrict__ Q, const float* __restrict__ TMat,
    const float* __restrict__ XT,
    unsigned short* __restrict__ Qb, unsigned short* __restrict__ Db,
    float* __restrict__ qn, float* __restrict__ dn)
{
    const int wid = threadIdx.x >> 6;
    const int lane = threadIdx.x & 63;
    const int row = blockIdx.x * 4 + wid;

    const float* src;
    unsigned short* dst;
    float* ndst;
    if (row < M_Q) {
        src = Q + (size_t)row * DIM; dst = Qb + (size_t)row * DIM; ndst = qn + row;
    } else {
        int r = row - M_Q;
        src = (row < M_Q + P_TM) ? (TMat + (size_t)r * DIM)
                                 : (XT + (size_t)(row - (M_Q + P_TM)) * DIM);
        dst = Db + (size_t)r * DIM; ndst = dn + r;
    }

    const float* p = src + lane * 8;
    float4 v0 = *(const float4*)p;
    float4 v1 = *(const float4*)(p + 4);
    float s = v0.x*v0.x + v0.y*v0.y + v0.z*v0.z + v0.w*v0.w
            + v1.x*v1.x + v1.y*v1.y + v1.z*v1.z + v1.w*v1.w;

    u16x8 o;
    o[0]=f2bf(v0.x); o[1]=f2bf(v0.y); o[2]=f2bf(v0.z); o[3]=f2bf(v0.w);
    o[4]=f2bf(v1.x); o[5]=f2bf(v1.y); o[6]=f2bf(v1.z); o[7]=f2bf(v1.w);
    *(u16x8*)(dst + lane * 8) = o;

    #pragma unroll
    for (int off = 32; off > 0; off >>= 1) s += __shfl_xor(s, off);
    if (lane == 0) *ndst = s;
}

// ---------------------------------------------------------------------------
// Pass 2: 64x64-tile MFMA distance + per-chunk top-2 (R8 structure).
// XCD-aware remap: bid = blockIdx.x (0..5119); xcd = bid&7; j = bid>>3;
//   mblk = j&15 (fast: sweep M for fixed B-tile), nchunk = (j>>4)*8 + xcd.
// On each XCD: 16 consecutive blocks reuse one 64KB B-tile (L2-hit) while
// the 1MB A panel cycles L2-resident.
// LDS: As/Bs [64 rows][64 bf16]; 16B chunk c of row r stored at c^(r&7).
// ---------------------------------------------------------------------------
__global__ __launch_bounds__(256, 8) void dist_mfma_kernel(
    const unsigned short* __restrict__ Qb,   // [M_Q][DIM] bf16
    const unsigned short* __restrict__ Db,   // [P_ALL][DIM] bf16
    const float* __restrict__ qn,            // [M_Q]
    const float* __restrict__ dn,            // [P_ALL]
    float* __restrict__ partial)             // [M_Q][NCHUNK_TOT][2]
{
    __shared__ __align__(16) unsigned short As[64 * 64];  // 8 KB
    __shared__ __align__(16) unsigned short Bs[64 * 64];  // 8 KB

    const int tid  = threadIdx.x;
    const int lane = tid & 63;
    const int wid  = tid >> 6;          // 0..3
    const int r15  = lane & 15;
    const int h    = lane >> 4;         // 0..3

    // --- XCD-aware sweep remap ---
    const int bid    = blockIdx.x;       // 0..5119
    const int xcd    = bid & 7;
    const int j      = bid >> 3;         // 0..639
    const int mblk   = j & 15;           // fast index: sweep M
    const int nchunk = ((j >> 4) << 3) + xcd;   // 0..319
    const int mBase  = mblk * 64;
    const int nBase  = nchunk * 64;

    // --- staging mapping: thread t -> row t>>2, chunks (t&3)*2, +1 ---
    const int srow  = tid >> 2;          // 0..63
    const int cpair = (tid & 3) * 2;     // 0,2,4,6
    const unsigned short* gA = Qb + (size_t)(mBase + srow) * DIM + cpair * 8;
    const unsigned short* gB = Db + (size_t)(nBase + srow) * DIM + cpair * 8;
    const int wA0 = srow * 64 + ((cpair       ^ (srow & 7)) << 3);
    const int wA1 = srow * 64 + (((cpair + 1) ^ (srow & 7)) << 3);

    // --- ds_read addresses (ushort idx); B: + n*1024 per 16-row group ---
    const int aA0 = (wid * 16 + r15) * 64 + (((h    ) ^ (r15 & 7)) << 3);
    const int aA1 = (wid * 16 + r15) * 64 + (((4 | h) ^ (r15 & 7)) << 3);
    const int bB0 = r15 * 64 + (((h    ) ^ (r15 & 7)) << 3);
    const int bB1 = r15 * 64 + (((4 | h) ^ (r15 & 7)) << 3);

    f32x4 acc0, acc1, acc2, acc3;
    #pragma unroll
    for (int i = 0; i < 4; ++i) { acc0[i]=0.f; acc1[i]=0.f; acc2[i]=0.f; acc3[i]=0.f; }

    // --- prologue: stage K-step 0 ---
    u16x8 pa0 = *(const u16x8*)(gA);
    u16x8 pa1 = *(const u16x8*)(gA + 8);
    u16x8 pb0 = *(const u16x8*)(gB);
    u16x8 pb1 = *(const u16x8*)(gB + 8);
    *(u16x8*)(&As[wA0]) = pa0;
    *(u16x8*)(&As[wA1]) = pa1;
    *(u16x8*)(&Bs[wA0]) = pb0;
    *(u16x8*)(&Bs[wA1]) = pb1;
    __syncthreads();

    #pragma unroll
    for (int t = 0; t < NSTEP; ++t) {
        if (t + 1 < NSTEP) {
            const int ko = (t + 1) * BK;
            pa0 = *(const u16x8*)(gA + ko);
            pa1 = *(const u16x8*)(gA + ko + 8);
            pb0 = *(const u16x8*)(gB + ko);
            pb1 = *(const u16x8*)(gB + ko + 8);
        }

        // kh = 0
        {
            bf16x8 af = *(const bf16x8*)(&As[aA0]);
            bf16x8 b0 = *(const bf16x8*)(&Bs[bB0]);
            bf16x8 b1 = *(const bf16x8*)(&Bs[bB0 + 1024]);
            bf16x8 b2 = *(const bf16x8*)(&Bs[bB0 + 2048]);
            bf16x8 b3 = *(const bf16x8*)(&Bs[bB0 + 3072]);
            acc0 = __builtin_amdgcn_mfma_f32_16x16x32_bf16(af, b0, acc0, 0, 0, 0);
            acc1 = __builtin_amdgcn_mfma_f32_16x16x32_bf16(af, b1, acc1, 0, 0, 0);
            acc2 = __builtin_amdgcn_mfma_f32_16x16x32_bf16(af, b2, acc2, 0, 0, 0);
            acc3 = __builtin_amdgcn_mfma_f32_16x16x32_bf16(af, b3, acc3, 0, 0, 0);
        }
        // kh = 1
        {
            bf16x8 af = *(const bf16x8*)(&As[aA1]);
            bf16x8 b0 = *(const bf16x8*)(&Bs[bB1]);
            bf16x8 b1 = *(const bf16x8*)(&Bs[bB1 + 1024]);
            bf16x8 b2 = *(const bf16x8*)(&Bs[bB1 + 2048]);
            bf16x8 b3 = *(const bf16x8*)(&Bs[bB1 + 3072]);
            acc0 = __builtin_amdgcn_mfma_f32_16x16x32_bf16(af, b0, acc0, 0, 0, 0);
            acc1 = __builtin_amdgcn_mfma_f32_16x16x32_bf16(af, b1, acc1, 0, 0, 0);
            acc2 = __builtin_amdgcn_mfma_f32_16x16x32_bf16(af, b2, acc2, 0, 0, 0);
            acc3 = __builtin_amdgcn_mfma_f32_16x16x32_bf16(af, b3, acc3, 0, 0, 0);
        }

        __syncthreads();                 // done reading LDS for step t

        if (t + 1 < NSTEP) {
            *(u16x8*)(&As[wA0]) = pa0;
            *(u16x8*)(&As[wA1]) = pa1;
            *(u16x8*)(&Bs[wA0]) = pb0;
            *(u16x8*)(&Bs[wA1]) = pb1;
            __syncthreads();             // LDS ready for step t+1
        }
    }

    // --- epilogue: row=rbase+r, col=nBase+nt*16+r15 ---
    const int rbase = mBase + wid * 16 + (h << 2);
    float q2[4];
    #pragma unroll
    for (int r = 0; r < 4; ++r) q2[r] = qn[rbase + r];

    float d1[4], d2[4];
    #pragma unroll
    for (int r = 0; r < 4; ++r) { d1[r] = BIGF; d2[r] = BIGF; }

    #pragma unroll
    for (int nt = 0; nt < 4; ++nt) {
        float dd = dn[nBase + nt * 16 + r15];
        const f32x4& a = (nt == 0) ? acc0 : (nt == 1) ? acc1 : (nt == 2) ? acc2 : acc3;
        #pragma unroll
        for (int r = 0; r < 4; ++r) {
            float sq = q2[r] + dd - 2.0f * a[r];
            sq = fmaxf(sq, 0.0f);
            merge1(sq, d1[r], d2[r]);
        }
    }

    #pragma unroll
    for (int r = 0; r < 4; ++r) top2_shfl16(d1[r], d2[r]);

    if (r15 == 0) {
        const int chunkG = nchunk;
        #pragma unroll
        for (int r = 0; r < 4; ++r) {
            size_t base = ((size_t)(rbase + r) * NCHUNK_TOT + chunkG) * 2;
            partial[base]     = d1[r];
            partial[base + 1] = d2[r];
        }
    }
}

// ---------------------------------------------------------------------------
// Pass 3: merge per-chunk top-2 partials (one wave per query).
// ---------------------------------------------------------------------------
__global__ __launch_bounds__(256) void reduce_top2_kernel(
    const float* __restrict__ partial, float* __restrict__ fin)
{
    const int wid  = threadIdx.x >> 6;
    const int lane = threadIdx.x & 63;
    const int m = blockIdx.x * 4 + wid;
    const float* p = partial + (size_t)m * (NCHUNK_TOT * 2);

    float2 v = *(const float2*)(p + 2 * lane);
    float a1 = fminf(v.x, v.y), a2 = fmaxf(v.x, v.y);
    #pragma unroll
    for (int off = 32; off > 0; off >>= 1) {
        float o1 = __shfl_xor(a1, off);
        float o2 = __shfl_xor(a2, off);
        float n1 = fminf(a1, o1);
        float n2 = fminf(fmaxf(a1, o1), fminf(a2, o2));
        a1 = n1; a2 = n2;
    }

    const float* px = p + 2 * NCHUNK_TM + lane * 8;
    float4 w0 = *(const float4*)px;
    float4 w1 = *(const float4*)(px + 4);
    float b1 = BIGF, b2 = BIGF;
    merge1(w0.x, b1, b2); merge1(w0.y, b1, b2);
    merge1(w0.z, b1, b2); merge1(w0.w, b1, b2);
    merge1(w1.x, b1, b2); merge1(w1.y, b1, b2);
    merge1(w1.z, b1, b2); merge1(w1.w, b1, b2);
    #pragma unroll
    for (int off = 32; off > 0; off >>= 1) {
        float o1 = __shfl_xor(b1, off);
        float o2 = __shfl_xor(b2, off);
        float n1 = fminf(b1, o1);
        float n2 = fminf(fmaxf(b1, o1), fminf(b2, o2));
        b1 = n1; b2 = n2;
    }

    if (lane == 0) {
        fin[m]           = sqrtf(a1);
        fin[M_Q + m]     = sqrtf(a2);
        fin[2*M_Q + m]   = sqrtf(b1);
        fin[3*M_Q + m]   = sqrtf(b2);
    }
}

// ---------------------------------------------------------------------------
// Pass 4: stats. Both percentile arrays sorted in ONE bitonic pass
// (same compare indices, two compare-exchanges per barrier step).
// ---------------------------------------------------------------------------
__global__ __launch_bounds__(1024) void stats_kernel(
    const float* __restrict__ fin, float* __restrict__ out)
{
    __shared__ float s0[1024];
    __shared__ float s1a[1024];
    __shared__ float red[16][6];
    const int t = threadIdx.x;

    float m1 = fin[t];
    float m2 = fin[1024 + t];
    float s1 = fin[2048 + t];
    float s2 = fin[3072 + t];

    const float T = 1.0f / 3.0f;
    float v[6];
    v[0] = (m1 < T * s1 && m1 < T * m2) ? 1.0f : 0.0f;
    v[1] = (s1 < T * m1 && s1 < T * s2) ? 1.0f : 0.0f;
    v[2] = m1; v[3] = s1; v[4] = m2; v[5] = s2;

    #pragma unroll
    for (int off = 32; off > 0; off >>= 1)
        #pragma unroll
        for (int i = 0; i < 6; ++i) v[i] += __shfl_xor(v[i], off);

    int lane = t & 63, wid = t >> 6;
    if (lane == 0) {
        #pragma unroll
        for (int i = 0; i < 6; ++i) red[wid][i] = v[i];
    }
    __syncthreads();
    if (t == 0) {
        float a[6] = {0, 0, 0, 0, 0, 0};
        for (int w = 0; w < 16; ++w)
            for (int i = 0; i < 6; ++i) a[i] += red[w][i];
        out[0] = a[0];
        out[1] = a[1];
        out[2] = a[2] / 1024.0f;
        out[3] = a[3] / 1024.0f;
        out[4] = a[4] / 1024.0f;
        out[5] = a[5] / 1024.0f;
    }

    s0[t]  = m1;
    s1a[t] = s1;
    __syncthreads();

    for (int k = 2; k <= 1024; k <<= 1) {
        for (int jj = k >> 1; jj > 0; jj >>= 1) {
            int ixj = t ^ jj;
            if (ixj > t) {
                bool up = ((t & k) == 0);
                float a = s0[t], b = s0[ixj];
                if ((a > b) == up) { s0[t] = b; s0[ixj] = a; }
                float c = s1a[t], d = s1a[ixj];
                if ((c > d) == up) { s1a[t] = d; s1a[ixj] = c; }
            }
            __syncthreads();
        }
    }

    if (t < 5) {
        const float P[5] = {10.f, 25.f, 50.f, 75.f, 90.f};
        float q = P[t] * 1023.0f / 100.0f;
        int lo = (int)q;
        float fr = q - (float)lo;
        out[6 + t]  = s0[lo]  + fr * (s0[lo + 1]  - s0[lo]);
        out[11 + t] = s1a[lo] + fr * (s1a[lo + 1] - s1a[lo]);
    }
}

// ---------------------------------------------------------------------------
// Fallback path (verified R2 kernels) — used only if ws_size is too small.
// ---------------------------------------------------------------------------
__global__ __launch_bounds__(256) void norms_kernel_fb(
    const float* __restrict__ src, float* __restrict__ dst, int nrows)
{
    int wid = threadIdx.x >> 6;
    int lane = threadIdx.x & 63;
    int row = blockIdx.x * 4 + wid;
    if (row >= nrows) return;
    const float* p = src + (size_t)row * DIM + lane * 8;
    float4 v0 = *(const float4*)p;
    float4 v1 = *(const float4*)(p + 4);
    float s = v0.x*v0.x + v0.y*v0.y + v0.z*v0.z + v0.w*v0.w
            + v1.x*v1.x + v1.y*v1.y + v1.z*v1.z + v1.w*v1.w;
    #pragma unroll
    for (int off = 32; off > 0; off >>= 1) s += __shfl_xor(s, off);
    if (lane == 0) dst[row] = s;
}

__global__ __launch_bounds__(256) void dist_top2_kernel_fb(
    const float* __restrict__ Q, const float* __restrict__ Dset,
    const float* __restrict__ qn, const float* __restrict__ dn,
    float* __restrict__ partial, int chunkGlobalOffset)
{
    __shared__ __align__(16) unsigned short As[64][40];
    __shared__ __align__(16) unsigned short Bs[64][40];

    const int tid  = threadIdx.x;
    const int lane = tid & 63;
    const int wid  = tid >> 6;
    const int mBase = blockIdx.y * 64;
    const int nBase = blockIdx.x * 64;

    const int srow = tid >> 2;
    const int skc  = (tid & 3) * 8;

    const float* qrow = Q    + (size_t)(mBase + srow) * DIM + skc;
    const float* drow = Dset + (size_t)(nBase + srow) * DIM + skc;

    f32x4 acc[4];
    #pragma unroll
    for (int nt = 0; nt < 4; ++nt)
        #pragma unroll
        for (int i = 0; i < 4; ++i) acc[nt][i] = 0.0f;

    const int frow = lane & 15;
    const int fk   = (lane >> 4) * 8;

    for (int ks = 0; ks < DIM; ks += 32) {
        float4 a0 = *(const float4*)(qrow + ks);
        float4 a1 = *(const float4*)(qrow + ks + 4);
        float4 b0 = *(const float4*)(drow + ks);
        float4 b1 = *(const float4*)(drow + ks + 4);

        u16x8 va, vb;
        va[0]=f2bf(a0.x); va[1]=f2bf(a0.y); va[2]=f2bf(a0.z); va[3]=f2bf(a0.w);
        va[4]=f2bf(a1.x); va[5]=f2bf(a1.y); va[6]=f2bf(a1.z); va[7]=f2bf(a1.w);
        vb[0]=f2bf(b0.x); vb[1]=f2bf(b0.y); vb[2]=f2bf(b0.z); vb[3]=f2bf(b0.w);
        vb[4]=f2bf(b1.x); vb[5]=f2bf(b1.y); vb[6]=f2bf(b1.z); vb[7]=f2bf(b1.w);

        *(u16x8*)(&As[srow][skc]) = va;
        *(u16x8*)(&Bs[srow][skc]) = vb;
        __syncthreads();

        bf16x8 af = *(const bf16x8*)(&As[wid * 16 + frow][fk]);
        #pragma unroll
        for (int nt = 0; nt < 4; ++nt) {
            bf16x8 bf = *(const bf16x8*)(&Bs[nt * 16 + frow][fk]);
            acc[nt] = __builtin_amdgcn_mfma_f32_16x16x32_bf16(af, bf, acc[nt], 0, 0, 0);
        }
        __syncthreads();
    }

    const int rbase = mBase + wid * 16 + ((lane >> 4) << 2);
    float q2[4];
    #pragma unroll
    for (int r = 0; r < 4; ++r) q2[r] = qn[rbase + r];

    float d1[4], d2[4];
    #pragma unroll
    for (int r = 0; r < 4; ++r) { d1[r] = BIGF; d2[r] = BIGF; }

    #pragma unroll
    for (int nt = 0; nt < 4; ++nt) {
        float dd = dn[nBase + nt * 16 + (lane & 15)];
        #pragma unroll
        for (int r = 0; r < 4; ++r) {
            float sq = q2[r] + dd - 2.0f * acc[nt][r];
            sq = fmaxf(sq, 0.0f);
            merge1(sq, d1[r], d2[r]);
        }
    }

    #pragma unroll
    for (int r = 0; r < 4; ++r) top2_shfl16(d1[r], d2[r]);

    if ((lane & 15) == 0) {
        int chunkG = chunkGlobalOffset + blockIdx.x;
        #pragma unroll
        for (int r = 0; r < 4; ++r) {
            size_t base = ((size_t)(rbase + r) * NCHUNK_TOT + chunkG) * 2;
            partial[base]     = d1[r];
            partial[base + 1] = d2[r];
        }
    }
}

// ---------------------------------------------------------------------------
extern "C" void kernel_launch(void* const* d_in, const int* in_sizes, int n_in,
                              void* d_out, int out_size, void* d_ws, size_t ws_size,
                              hipStream_t stream) {
    const float* Q  = (const float*)d_in[0];
    const float* TM = (const float*)d_in[1];
    const float* XT = (const float*)d_in[2];
    float* out = (float*)d_out;

    const size_t needMain =
        (size_t)M_Q * DIM * 2 + (size_t)P_ALL * DIM * 2 +
        4 * ((size_t)M_Q + P_ALL + (size_t)M_Q * NCHUNK_TOT * 2 + 4 * M_Q);

    if (ws_size >= needMain) {
        char* w = (char*)d_ws;
        unsigned short* Qb = (unsigned short*)w;
        unsigned short* Db = (unsigned short*)(w + (size_t)M_Q * DIM * 2);
        float* qn = (float*)(w + (size_t)M_Q * DIM * 2 + (size_t)P_ALL * DIM * 2);
        float* dn = qn + M_Q;
        float* partial = dn + P_ALL;
        float* fin = partial + (size_t)M_Q * NCHUNK_TOT * 2;

        convert_norms_kernel<<<dim3(NROWS_ALL / 4), 256, 0, stream>>>(
            Q, TM, XT, Qb, Db, qn, dn);
        dist_mfma_kernel<<<dim3(NCHUNK_TOT * (M_Q / 64)), 256, 0, stream>>>(
            Qb, Db, qn, dn, partial);
        reduce_top2_kernel<<<dim3(M_Q / 4), 256, 0, stream>>>(partial, fin);
        stats_kernel<<<dim3(1), 1024, 0, stream>>>(fin, out);
    } else {
        float* ws = (float*)d_ws;
        float* qn = ws;
        float* dn = ws + M_Q;
        float* partial = dn + P_ALL;
        float* fin = partial + (size_t)M_Q * NCHUNK_TOT * 2;

        norms_kernel_fb<<<dim3(M_Q / 4),  256, 0, stream>>>(Q,  qn, M_Q);
        norms_kernel_fb<<<dim3(P_TM / 4), 256, 0, stream>>>(TM, dn, P_TM);
        norms_kernel_fb<<<dim3(P_XT / 4), 256, 0, stream>>>(XT, dn + P_TM, P_XT);
        dist_top2_kernel_fb<<<dim3(P_TM / 64, M_Q / 64), 256, 0, stream>>>(
            Q, TM, qn, dn, partial, 0);
        dist_top2_kernel_fb<<<dim3(P_XT / 64, M_Q / 64), 256, 0, stream>>>(
            Q, XT, qn, dn + P_TM, partial, NCHUNK_TM);
        reduce_top2_kernel<<<dim3(M_Q / 4), 256, 0, stream>>>(partial, fin);
        stats_kernel<<<dim3(1), 1024, 0, stream>>>(fin, out);
    }
}